// Round 12
// baseline (184.889 us; speedup 1.0000x reference)
//
#include <hip/hip_runtime.h>
#include <hip/hip_bf16.h>

// GraphAutoencoder: 3x GraphConv (DGL norm='both') on fixed graph.
// N=50000 nodes, E=600000 edges, widths 128 -> 64 -> 32 -> 128.
//
// R1..R6: scatter->CSR gather, bf16 tables, row-local fusion: 485->213us.
// R7: degree-sort perm REGRESSED (locality). R8: 2-way edge split -> 202us.
// R9: pad-to-16 + 4-way edge split, u8 slab, u16 csr -> 191us.
// R10: MFMA GEMM-A, 32-node B/D blocks, src-hist 32 partitions -> 186us.
// R11: seg[](start,qlen) uint2 + batched seg preloads -> 183us.
//     (harness 0xAA poison of 256MiB ws+32MB out = ~49us fixed in window)
// R12: t1 column-split into two 32-wide tables (3.2MB each). B gathers in
//      two phases, one table per phase -> per-phase working set fits the
//      4MiB per-XCD L2 (6.4MB table was thrashing it). Same loads, same
//      arithmetic order (bit-identical output), better locality.
//
// Pipeline:
//   A: t1{lo,hi} = bf16(rs_out .* (X @ W1))                [MFMA GEMM]
//   B: agg=gather(t1lo)+gather(t1hi); h=relu(rs_in*agg+b1);
//      t2b = bf16(rs_out .* (h @ W2))                      [fused]
//   C: z = rs_in*gather(t2b)+b2 -> d_out; zb = bf16(z*rs_out)
//   D: recon = (rs_in .* gather(zb)) @ W3 + b3 -> d_out    [fused]

#define NN   50000     // nodes (fixed by problem)
#define HPS  32        // src edge partitions (sum only)
#define HPD  128       // dst edge partitions (must match fill)
#define FNB  2         // fill node bins
#define FBIN 25000     // nodes per fill bin
typedef unsigned short u16;
typedef unsigned char  u8;
typedef __attribute__((ext_vector_type(8))) short bf16x8;
typedef __attribute__((ext_vector_type(4))) float f32x4;

__device__ __forceinline__ float bfhi(unsigned u) {
    unsigned v = u & 0xFFFF0000u;
    return __builtin_bit_cast(float, v);
}
__device__ __forceinline__ float bflo(unsigned u) {
    unsigned v = u << 16;
    return __builtin_bit_cast(float, v);
}
__device__ __forceinline__ unsigned f2bf(float f) {   // f32 -> bf16 RNE
    unsigned u = __builtin_bit_cast(unsigned, f);
    return (u + 0x7FFFu + ((u >> 16) & 1u)) >> 16;
}

// ---------------- histogram: u8 slab[HPS+HPD][NN], packed-u8 LDS ----------------
__global__ __launch_bounds__(256) void k_hist1(
    const int* __restrict__ src, const int* __restrict__ dst,
    u8* __restrict__ slab, int E, int slice_s, int slice_d)
{
    __shared__ unsigned h[NN / 4];               // 50KB, 4 u8 counters per word
    const bool is_src = blockIdx.x < HPS;
    const int p       = is_src ? blockIdx.x : blockIdx.x - HPS;
    const int slice   = is_src ? slice_s : slice_d;
    const int* __restrict__ idx = is_src ? src : dst;

    for (int i = threadIdx.x; i < NN / 4; i += 256) h[i] = 0;
    __syncthreads();

    const int beg = p * slice;
    const int fin = min(beg + slice, E);
    for (int i = beg + threadIdx.x * 4; i + 3 < fin; i += 1024) {
        const int4 v = *(const int4*)(idx + i);
        atomicAdd(&h[v.x >> 2], 1u << ((v.x & 3) << 3));
        atomicAdd(&h[v.y >> 2], 1u << ((v.y & 3) << 3));
        atomicAdd(&h[v.z >> 2], 1u << ((v.z & 3) << 3));
        atomicAdd(&h[v.w >> 2], 1u << ((v.w & 3) << 3));
    }
    for (int i = beg + ((fin - beg) & ~3) + threadIdx.x; i < fin; i += 256) {
        const int u = idx[i];
        atomicAdd(&h[u >> 2], 1u << ((u & 3) << 3));
    }
    __syncthreads();

    unsigned* out = (unsigned*)(slab + (size_t)blockIdx.x * NN);  // NN%4==0
    for (int i = threadIdx.x; i < NN / 4; i += 256) out[i] = h[i];
}

// degrees -> rsqrt; dst half -> per-partition exclusive u8 offsets (in place);
// block-level inclusive scan of PADDED in-degree; pad4 export; csr dummy-init.
__global__ __launch_bounds__(256) void k_reduce_scan(
    u8* __restrict__ slab, float* __restrict__ rs_out, float* __restrict__ rs_in,
    int* __restrict__ partial, int* __restrict__ blocksum, u8* __restrict__ pad4,
    unsigned* __restrict__ csr_words, int ncw, int N)
{
    __shared__ int tmp[256];
    const int tid = threadIdx.x;
    const int i = blockIdx.x * 256 + tid;

    int run = 0;
    if (i < N) {
        const u8* s_src = slab + i;
        u8*       s_dst = slab + (size_t)HPS * NN + i;
        int so = 0;
#pragma unroll 8
        for (int p = 0; p < HPS; ++p) so += s_src[(size_t)p * NN];
#pragma unroll 8
        for (int p = 0; p < HPD; ++p) {
            const int c = s_dst[(size_t)p * NN];
            s_dst[(size_t)p * NN] = (u8)run;
            run += c;
        }
        rs_out[i] = rsqrtf(fmaxf((float)so, 1.0f));
        rs_in[i]  = rsqrtf(fmaxf((float)run, 1.0f));
    }
    const int pad = (run + 15) & ~15;            // pad degree to mult of 16
    if (i < N) pad4[i] = (u8)(pad >> 2);         // quarter length in entries
    tmp[tid] = pad; __syncthreads();
    for (int off = 1; off < 256; off <<= 1) {
        int t = (tid >= off) ? tmp[tid - off] : 0;
        __syncthreads(); tmp[tid] += t; __syncthreads();
    }
    if (i < N) partial[i] = tmp[tid];
    if (tid == 255) blocksum[blockIdx.x] = tmp[255];

    // dummy-init padded csr: every slot = node id NN (the zero row)
    for (int w = blockIdx.x * 256 + tid; w < ncw; w += gridDim.x * 256)
        csr_words[w] = 0xC350C350u;              // 0xC350 == 50000 == NN
}

// Fused scan2+scan3 -> seg[node] = (start, quarter_len_entries) uint2.
__global__ __launch_bounds__(256) void k_scan23(
    const int* __restrict__ partial, const int* __restrict__ blocksum,
    const u8* __restrict__ pad4, uint2* __restrict__ seg, int n, int nb)
{
    __shared__ int tmp[256];
    const int tid = threadIdx.x;
    int v = (tid < nb) ? blocksum[tid] : 0;
    tmp[tid] = v; __syncthreads();
    for (int off = 1; off < 256; off <<= 1) {
        int t = (tid >= off) ? tmp[tid - off] : 0;
        __syncthreads(); tmp[tid] += t; __syncthreads();
    }
    __syncthreads();
    const int i = blockIdx.x * 256 + tid;
    if (i < n) {
        const int base = (blockIdx.x > 0) ? tmp[blockIdx.x - 1] : 0;
        const int incl = partial[i] + base;
        const unsigned q = pad4[i];
        seg[i] = make_uint2((unsigned)(incl - (int)(q << 2)), q);
    }
}

// ---------- CSR fill: LDS cursors, u16 entries (zero global atomics) ----------
__global__ __launch_bounds__(256) void k_fill2(
    const int* __restrict__ src, const int* __restrict__ dst,
    const uint2* __restrict__ seg, const u8* __restrict__ slab,
    u16* __restrict__ csr, int E, int slice, int N)
{
    __shared__ int cur[FBIN];                    // 100KB
    const int bin = blockIdx.x / HPD;
    const int p   = blockIdx.x % HPD;
    const int lo  = bin * FBIN;

    const u8* part_off = slab + (size_t)(HPS + p) * NN;   // dst half, partition p
    for (int j = threadIdx.x; j < FBIN; j += 256) {
        const int node = lo + j;
        cur[j] = (int)seg[node].x + (int)part_off[node];
    }
    __syncthreads();

    const int beg = p * slice;
    const int fin = min(beg + slice, E);
    for (int i = beg + threadIdx.x * 4; i + 3 < fin; i += 1024) {
        const int4 d = *(const int4*)(dst + i);
        const int4 s = *(const int4*)(src + i);
        int u;
        u = d.x - lo; if ((unsigned)u < (unsigned)FBIN) csr[atomicAdd(&cur[u], 1)] = (u16)s.x;
        u = d.y - lo; if ((unsigned)u < (unsigned)FBIN) csr[atomicAdd(&cur[u], 1)] = (u16)s.y;
        u = d.z - lo; if ((unsigned)u < (unsigned)FBIN) csr[atomicAdd(&cur[u], 1)] = (u16)s.z;
        u = d.w - lo; if ((unsigned)u < (unsigned)FBIN) csr[atomicAdd(&cur[u], 1)] = (u16)s.w;
    }
    for (int i = beg + ((fin - beg) & ~3) + threadIdx.x; i < fin; i += 256) {
        int u = dst[i] - lo;
        if ((unsigned)u < (unsigned)FBIN) csr[atomicAdd(&cur[u], 1)] = (u16)src[i];
    }
}

// ---------------- MFMA GEMM A: t1{lo,hi} = bf16(rs_out .* (X @ W1)) ----------------
#define XS1 136    // padded bf16 row stride
__global__ __launch_bounds__(256) void k_gemm_mfma_A(
    const float* __restrict__ X, const float* __restrict__ W1,
    const float* __restrict__ rs, u16* __restrict__ t1lo, u16* __restrict__ t1hi,
    u16* __restrict__ t2b, u16* __restrict__ zb, int N)
{
    __shared__ u16 sXb[64 * XS1];     // X rows, bf16
    __shared__ u16 sWt[64 * XS1];     // W1^T: [n][k], bf16
    const int tid = threadIdx.x;
    const int m0 = blockIdx.x * 64;

    if (blockIdx.x == 0) {            // zero dummy rows (id NN)
        if (tid < 16)      ((unsigned*)(t1lo + (size_t)NN * 32))[tid]      = 0;
        else if (tid < 32) ((unsigned*)(t1hi + (size_t)NN * 32))[tid - 16] = 0;
        else if (tid < 48) ((unsigned*)(t2b  + (size_t)NN * 32))[tid - 32] = 0;
        else if (tid < 64) ((unsigned*)(zb   + (size_t)NN * 32))[tid - 48] = 0;
    }

    for (int i = tid; i < 128 * 64; i += 256) {
        const int k = i >> 6, n = i & 63;
        sWt[n * XS1 + k] = (u16)f2bf(W1[i]);
    }
    for (int i = tid; i < 64 * 32; i += 256) {       // 64 rows x 32 float4-chunks
        const int r  = i >> 5;
        const int c4 = (i & 31) * 4;
        const int gr = m0 + r;
        float4 v = make_float4(0.f, 0.f, 0.f, 0.f);
        if (gr < N) v = *(const float4*)(X + (size_t)gr * 128 + c4);
        uint2 pk;
        pk.x = f2bf(v.x) | (f2bf(v.y) << 16);
        pk.y = f2bf(v.z) | (f2bf(v.w) << 16);
        *(uint2*)(sXb + r * XS1 + c4) = pk;
    }
    __syncthreads();

    const int wv   = tid >> 6;
    const int lane = tid & 63;
    const int l15  = lane & 15;
    const int quad = lane >> 4;

    f32x4 acc[4] = {};
    const u16* ax = sXb + (wv * 16 + l15) * XS1 + quad * 8;
    const u16* bx = sWt + l15 * XS1 + quad * 8;
#pragma unroll
    for (int ks = 0; ks < 4; ++ks) {
        const bf16x8 af = *(const bf16x8*)(ax + ks * 32);
#pragma unroll
        for (int nt = 0; nt < 4; ++nt) {
            const bf16x8 bf = *(const bf16x8*)(bx + nt * 16 * XS1 + ks * 32);
            acc[nt] = __builtin_amdgcn_mfma_f32_16x16x32_bf16(af, bf, acc[nt], 0, 0, 0);
        }
    }

    const int mrow = m0 + wv * 16 + quad * 4;
    float sc[4];
#pragma unroll
    for (int r = 0; r < 4; ++r) sc[r] = (mrow + r < N) ? rs[mrow + r] : 0.f;
#pragma unroll
    for (int r = 0; r < 4; ++r) {
        const int gr = mrow + r;
        if (gr < N) {
            // nt 0,1 -> cols 0..31 (t1lo); nt 2,3 -> cols 32..63 (t1hi)
            t1lo[(size_t)gr * 32 +  0 + l15] = (u16)f2bf(acc[0][r] * sc[r]);
            t1lo[(size_t)gr * 32 + 16 + l15] = (u16)f2bf(acc[1][r] * sc[r]);
            t1hi[(size_t)gr * 32 +  0 + l15] = (u16)f2bf(acc[2][r] * sc[r]);
            t1hi[(size_t)gr * 32 + 16 + l15] = (u16)f2bf(acc[3][r] * sc[r]);
        }
    }
}

// accumulate one bf16x8 row chunk
#define ACC8(q) do { \
    a[0] += bflo((q).x); a[1] += bfhi((q).x); a[2] += bflo((q).y); a[3] += bfhi((q).y); \
    a[4] += bflo((q).z); a[5] += bfhi((q).z); a[6] += bflo((q).w); a[7] += bfhi((q).w); } while (0)

// gather 4 padded edges: 1 uint2 index load + 4 row loads
#define GATHER4(SRCB, RW) do { \
    const uint2 w = *(const uint2*)(csr + j); \
    const int s0 = w.x & 0xFFFF, s1 = w.x >> 16; \
    const int s2 = w.y & 0xFFFF, s3 = w.y >> 16; \
    const uint4 q0 = *(const uint4*)(SRCB + (size_t)s0 * RW + c8); \
    const uint4 q1 = *(const uint4*)(SRCB + (size_t)s1 * RW + c8); \
    const uint4 q2 = *(const uint4*)(SRCB + (size_t)s2 * RW + c8); \
    const uint4 q3 = *(const uint4*)(SRCB + (size_t)s3 * RW + c8); \
    ACC8(q0); ACC8(q1); ACC8(q2); ACC8(q3); } while (0)

// ---------------- fused B: gather(t1lo)+gather(t1hi) + relu + @W2 -> t2b ----------------
// 32 nodes/block. Two phases (one 3.2MB table each, L2-resident); per phase
// 2 batches of 16 nodes x 16 lanes (4 col-lanes x 4 edge-quarters).
__global__ __launch_bounds__(256) void k_gather_gemm_B(
    const uint2* __restrict__ seg, const u16* __restrict__ csr,
    const u16* __restrict__ t1lo, const u16* __restrict__ t1hi,
    const float* __restrict__ rs_in, const float* __restrict__ rs_out,
    const float* __restrict__ b1, const float* __restrict__ W2,
    u16* __restrict__ t2b, int N)
{
    __shared__ float sh[32][72];
    __shared__ float sW[64 * 32];
    const int tid = threadIdx.x;

    for (int i = tid; i < 64 * 32 / 4; i += 256)
        ((float4*)sW)[i] = ((const float4*)W2)[i];

    const int nb   = tid >> 4;           // 16 node-groups in flight
    const int sub  = tid & 15;
    const int qtr  = sub >> 2;
    const int c8   = (sub & 3) * 8;

    uint2 sgs[2];                        // preload both batches' segments
#pragma unroll
    for (int b = 0; b < 2; ++b) {
        const int node = blockIdx.x * 32 + b * 16 + nb;
        sgs[b] = (node < N) ? seg[node] : make_uint2(0u, 0u);
    }

#pragma unroll
    for (int ph = 0; ph < 2; ++ph) {
        const u16* __restrict__ tab = ph ? t1hi : t1lo;
#pragma unroll
        for (int b = 0; b < 2; ++b) {
            const int nloc = b * 16 + nb;
            const int node = blockIdx.x * 32 + nloc;
            float a[8];
#pragma unroll
            for (int t = 0; t < 8; ++t) a[t] = 0.f;
            const int j0 = (int)sgs[b].x + qtr * (int)sgs[b].y;
            const int j1 = j0 + (int)sgs[b].y;
            for (int j = j0; j < j1; j += 4) GATHER4(tab, 32);
#pragma unroll
            for (int t = 0; t < 8; ++t) {
                a[t] += __shfl_xor(a[t], 4);
                a[t] += __shfl_xor(a[t], 8);
            }
            if (node < N && qtr == 0) {
                const float rs = rs_in[node];
                const int cc = ph * 32 + c8;
#pragma unroll
                for (int t = 0; t < 8; ++t)
                    sh[nloc][cc + t] = fmaxf(a[t] * rs + b1[cc + t], 0.f);
            }
        }
    }
    __syncthreads();

    // GEMM: 32 nodes x 32 cols; all 256 threads (node=tid/8, 4 cols each)
    const int n2 = tid >> 3;
    const int c4 = (tid & 7) * 4;
    float4 acc = make_float4(0.f, 0.f, 0.f, 0.f);
#pragma unroll 8
    for (int k = 0; k < 64; ++k) {
        const float xv = sh[n2][k];
        const float4 w = *(const float4*)(sW + k * 32 + c4);
        acc.x += xv * w.x; acc.y += xv * w.y; acc.z += xv * w.z; acc.w += xv * w.w;
    }
    const int gn = blockIdx.x * 32 + n2;
    if (gn < N) {
        const float s = rs_out[gn];
        uint2 pk;
        pk.x = f2bf(acc.x * s) | (f2bf(acc.y * s) << 16);
        pk.y = f2bf(acc.z * s) | (f2bf(acc.w * s) << 16);
        *(uint2*)(t2b + (size_t)gn * 32 + c4) = pk;
    }
}

// ---------------- C: gather(t2b,32) -> z (f32, d_out) + zb shadow ----------------
// 16 lanes/node = 4 col-lanes x 4 edge-quarters; combine via shfl_xor 4,8.
__global__ __launch_bounds__(256) void k_gather_C(
    const uint2* __restrict__ seg, const u16* __restrict__ csr,
    const u16* __restrict__ t2b, const float* __restrict__ rs_in,
    const float* __restrict__ rs_out, const float* __restrict__ b2,
    float* __restrict__ z, u16* __restrict__ zb, int N)
{
    const int node = blockIdx.x * 16 + (threadIdx.x >> 4);
    const int sub  = threadIdx.x & 15;
    const int qtr  = sub >> 2;
    const int c8   = (sub & 3) * 8;
    if (node >= N) return;               // 16-lane group exits together

    const uint2 sg = seg[node];
    const int j0 = (int)sg.x + qtr * (int)sg.y;
    const int j1 = j0 + (int)sg.y;

    float a[8];
#pragma unroll
    for (int t = 0; t < 8; ++t) a[t] = 0.f;
    for (int j = j0; j < j1; j += 4) GATHER4(t2b, 32);

#pragma unroll
    for (int t = 0; t < 8; ++t) {
        a[t] += __shfl_xor(a[t], 4);
        a[t] += __shfl_xor(a[t], 8);
    }
    if (qtr) return;

    const float rs = rs_in[node];
    float v[8];
#pragma unroll
    for (int t = 0; t < 8; ++t) v[t] = a[t] * rs + b2[c8 + t];

    float* o = z + (size_t)node * 32 + c8;
    *(float4*)(o)     = make_float4(v[0], v[1], v[2], v[3]);
    *(float4*)(o + 4) = make_float4(v[4], v[5], v[6], v[7]);

    const float ss = rs_out[node];
    uint4 pk;
    pk.x = f2bf(v[0] * ss) | (f2bf(v[1] * ss) << 16);
    pk.y = f2bf(v[2] * ss) | (f2bf(v[3] * ss) << 16);
    pk.z = f2bf(v[4] * ss) | (f2bf(v[5] * ss) << 16);
    pk.w = f2bf(v[6] * ss) | (f2bf(v[7] * ss) << 16);
    *(uint4*)(zb + (size_t)node * 32 + c8) = pk;
}

// ---------------- fused D: gather(zb,32) + @W3 + b3 -> recon ----------------
// 32 nodes/block: 2 gather batches (16 nodes x 16 lanes), then 256-thread GEMM.
__global__ __launch_bounds__(256) void k_gather_gemm_D(
    const uint2* __restrict__ seg, const u16* __restrict__ csr,
    const u16* __restrict__ zb, const float* __restrict__ rs_in,
    const float* __restrict__ W3, const float* __restrict__ b3,
    float* __restrict__ recon, int N)
{
    __shared__ float sa[32][36];
    __shared__ float sW[32 * 128];
    const int tid = threadIdx.x;

    for (int i = tid; i < 32 * 128 / 4; i += 256)
        ((float4*)sW)[i] = ((const float4*)W3)[i];

    const int nb   = tid >> 4;           // 16 node-groups in flight
    const int sub  = tid & 15;
    const int qtr  = sub >> 2;
    const int c8   = (sub & 3) * 8;

    uint2 sgs[2];                        // preload both batches' segments
#pragma unroll
    for (int b = 0; b < 2; ++b) {
        const int node = blockIdx.x * 32 + b * 16 + nb;
        sgs[b] = (node < N) ? seg[node] : make_uint2(0u, 0u);
    }

#pragma unroll
    for (int b = 0; b < 2; ++b) {
        const int nloc = b * 16 + nb;
        const int node = blockIdx.x * 32 + nloc;
        float a[8];
#pragma unroll
        for (int t = 0; t < 8; ++t) a[t] = 0.f;
        const int j0 = (int)sgs[b].x + qtr * (int)sgs[b].y;
        const int j1 = j0 + (int)sgs[b].y;
        for (int j = j0; j < j1; j += 4) GATHER4(zb, 32);
#pragma unroll
        for (int t = 0; t < 8; ++t) {
            a[t] += __shfl_xor(a[t], 4);
            a[t] += __shfl_xor(a[t], 8);
        }
        if (node < N && qtr == 0) {
            const float rs = rs_in[node];
#pragma unroll
            for (int t = 0; t < 8; ++t) sa[nloc][c8 + t] = a[t] * rs;
        }
    }
    __syncthreads();

    // GEMM: 32 nodes x 128 cols; thread -> 4 nodes x 4 cols
    const int ng = (tid >> 5) * 4;
    const int c4 = (tid & 31) * 4;
    const float4 bb = *(const float4*)(b3 + c4);
    float4 acc[4];
#pragma unroll
    for (int i = 0; i < 4; ++i) acc[i] = bb;
#pragma unroll 4
    for (int k = 0; k < 32; ++k) {
        const float4 w = *(const float4*)(sW + k * 128 + c4);
#pragma unroll
        for (int i = 0; i < 4; ++i) {
            const float xv = sa[ng + i][k];
            acc[i].x += xv * w.x; acc[i].y += xv * w.y;
            acc[i].z += xv * w.z; acc[i].w += xv * w.w;
        }
    }
#pragma unroll
    for (int i = 0; i < 4; ++i) {
        const int gn = blockIdx.x * 32 + ng + i;
        if (gn < N) *(float4*)(recon + (size_t)gn * 128 + c4) = acc[i];
    }
}

extern "C" void kernel_launch(void* const* d_in, const int* in_sizes, int n_in,
                              void* d_out, int out_size, void* d_ws, size_t ws_size,
                              hipStream_t stream) {
    const float* feat = (const float*)d_in[0];   // [N,128]
    const int*   src  = (const int*)d_in[1];     // [E]
    const int*   dst  = (const int*)d_in[2];     // [E]
    const float* W1   = (const float*)d_in[3];   // [128,64]
    const float* b1   = (const float*)d_in[4];   // [64]
    const float* W2   = (const float*)d_in[5];   // [64,32]
    const float* b2   = (const float*)d_in[6];   // [32]
    const float* W3   = (const float*)d_in[7];   // [32,128]
    const float* b3   = (const float*)d_in[8];   // [128]

    const int E = in_sizes[1];
    const int N = in_sizes[0] / 128;             // 50000 == NN
    const int slice_s = (((E + HPS - 1) / HPS) + 3) & ~3;
    const int slice_d = (((E + HPD - 1) / HPD) + 3) & ~3;
    const int CSRMAX = E + 15 * N;               // padded-csr upper bound (entries)
    const int ncw = CSRMAX / 2;                  // u32 words

    // ---- workspace layout (16B alignment at every boundary) ----
    const size_t SLABB = (size_t)(HPS + HPD) * NN;  // u8 slab = 8MB
    u8*  slab     = (u8*)d_ws;                    // dead after k_fill2
    uint2* seg    = (uint2*)(slab + SLABB);       // [N+16] (start, qlen)
    int* scan_p   = (int*)(seg + N + 16);         // [N]
    int* blocksum = scan_p + N;                   // [256]
    u16* csr      = (u16*)(blocksum + 256);       // [CSRMAX] u16 node ids
    float* rs_out = (float*)(csr + CSRMAX);       // [N]
    float* rs_in  = rs_out + N;                   // [N]
    u16* t2b      = (u16*)(rs_in + N);            // [(N+8),32] bf16 (+dummy row N)
    u16* zb       = t2b + (size_t)(N + 8) * 32;   // [(N+8),32] bf16 (z * rs_out)
    u8*  pad4     = (u8*)(zb + (size_t)(N + 8) * 32);  // [N] quarter lengths
    u16* t1lo     = (u16*)slab;                   // [(N+8),32] bf16, aliases slab
    u16* t1hi     = t1lo + (size_t)(NN + 8) * 32; // [(N+8),32] bf16 (6.4MB <= 8MB)

    float* z_out  = (float*)d_out;                // [N,32]
    float* recon  = z_out + (size_t)N * 32;       // [N,128]

    const int B = 256;
    const int nb_scan = (N + 255) / 256;          // 196

    // ---- atomic-free graph preprocessing (padded CSR, u8 counts, u16 ids) ----
    k_hist1<<<HPS + HPD, B, 0, stream>>>(src, dst, slab, E, slice_s, slice_d);
    k_reduce_scan<<<nb_scan, B, 0, stream>>>(slab, rs_out, rs_in, scan_p, blocksum,
                                             pad4, (unsigned*)csr, ncw, N);
    k_scan23<<<nb_scan, B, 0, stream>>>(scan_p, blocksum, pad4, seg, N, nb_scan);
    k_fill2<<<FNB * HPD, B, 0, stream>>>(src, dst, seg, slab, csr, E, slice_d, N);

    // ---- A: t1{lo,hi} = bf16(rs_out .* (X @ W1)) via MFMA; zero dummy rows ----
    k_gemm_mfma_A<<<(N + 63) / 64, B, 0, stream>>>(
        feat, W1, rs_out, t1lo, t1hi, t2b, zb, N);

    // ---- B: gather(t1lo)+gather(t1hi) + relu + @W2 -> t2b ----
    k_gather_gemm_B<<<(N + 31) / 32, B, 0, stream>>>(
        seg, csr, t1lo, t1hi, rs_in, rs_out, b1, W2, t2b, N);

    // ---- C: gather(t2b) -> z (d_out) + zb shadow ----
    k_gather_C<<<(N + 15) / 16, B, 0, stream>>>(
        seg, csr, t2b, rs_in, rs_out, b2, z_out, zb, N);

    // ---- D: gather(zb) + @W3 + b3 -> recon ----
    k_gather_gemm_D<<<(N + 31) / 32, B, 0, stream>>>(
        seg, csr, zb, rs_in, W3, b3, recon, N);
}

// Round 13
// 181.146 us; speedup vs baseline: 1.0207x; 1.0207x over previous
//
#include <hip/hip_runtime.h>
#include <hip/hip_bf16.h>

// GraphAutoencoder: 3x GraphConv (DGL norm='both') on fixed graph.
// N=50000 nodes, E=600000 edges, widths 128 -> 64 -> 32 -> 128.
//
// R1..R6: scatter->CSR gather, bf16 tables, row-local fusion: 485->213us.
// R7: degree-sort perm REGRESSED (locality). R8: 2-way edge split -> 202us.
// R9: pad-to-16 + 4-way edge split, u8 slab, u16 csr -> 191us.
// R10: MFMA GEMM-A, 32-node B/D blocks, src-hist 32 partitions -> 186us.
// R11: seg[](start,qlen) uint2 + batched seg preloads -> 183us.
// R12: t1 column-split (L2-capacity theory) NEUTRAL/regressed (185us):
//      gathers are latency-saturated, not L2-capacity bound. REVERTED.
// R13: exact R11 structure restored (best known config).
//     (harness 0xAA poison of 256MiB ws+32MB out = ~49us fixed in window)
//
// Pipeline:
//   A: t1b = bf16(rs_out .* (X @ W1))                      [MFMA GEMM]
//   B: agg=gather(t1b); h=relu(rs_in*agg+b1);
//      t2b = bf16(rs_out .* (h @ W2))                      [fused]
//   C: z = rs_in*gather(t2b)+b2 -> d_out; zb = bf16(z*rs_out)
//   D: recon = (rs_in .* gather(zb)) @ W3 + b3 -> d_out    [fused]

#define NN   50000     // nodes (fixed by problem)
#define HPS  32        // src edge partitions (sum only)
#define HPD  128       // dst edge partitions (must match fill)
#define FNB  2         // fill node bins
#define FBIN 25000     // nodes per fill bin
typedef unsigned short u16;
typedef unsigned char  u8;
typedef __attribute__((ext_vector_type(8))) short bf16x8;
typedef __attribute__((ext_vector_type(4))) float f32x4;

__device__ __forceinline__ float bfhi(unsigned u) {
    unsigned v = u & 0xFFFF0000u;
    return __builtin_bit_cast(float, v);
}
__device__ __forceinline__ float bflo(unsigned u) {
    unsigned v = u << 16;
    return __builtin_bit_cast(float, v);
}
__device__ __forceinline__ unsigned f2bf(float f) {   // f32 -> bf16 RNE
    unsigned u = __builtin_bit_cast(unsigned, f);
    return (u + 0x7FFFu + ((u >> 16) & 1u)) >> 16;
}

// ---------------- histogram: u8 slab[HPS+HPD][NN], packed-u8 LDS ----------------
__global__ __launch_bounds__(256) void k_hist1(
    const int* __restrict__ src, const int* __restrict__ dst,
    u8* __restrict__ slab, int E, int slice_s, int slice_d)
{
    __shared__ unsigned h[NN / 4];               // 50KB, 4 u8 counters per word
    const bool is_src = blockIdx.x < HPS;
    const int p       = is_src ? blockIdx.x : blockIdx.x - HPS;
    const int slice   = is_src ? slice_s : slice_d;
    const int* __restrict__ idx = is_src ? src : dst;

    for (int i = threadIdx.x; i < NN / 4; i += 256) h[i] = 0;
    __syncthreads();

    const int beg = p * slice;
    const int fin = min(beg + slice, E);
    for (int i = beg + threadIdx.x * 4; i + 3 < fin; i += 1024) {
        const int4 v = *(const int4*)(idx + i);
        atomicAdd(&h[v.x >> 2], 1u << ((v.x & 3) << 3));
        atomicAdd(&h[v.y >> 2], 1u << ((v.y & 3) << 3));
        atomicAdd(&h[v.z >> 2], 1u << ((v.z & 3) << 3));
        atomicAdd(&h[v.w >> 2], 1u << ((v.w & 3) << 3));
    }
    for (int i = beg + ((fin - beg) & ~3) + threadIdx.x; i < fin; i += 256) {
        const int u = idx[i];
        atomicAdd(&h[u >> 2], 1u << ((u & 3) << 3));
    }
    __syncthreads();

    unsigned* out = (unsigned*)(slab + (size_t)blockIdx.x * NN);  // NN%4==0
    for (int i = threadIdx.x; i < NN / 4; i += 256) out[i] = h[i];
}

// degrees -> rsqrt; dst half -> per-partition exclusive u8 offsets (in place);
// block-level inclusive scan of PADDED in-degree; pad4 export; csr dummy-init.
__global__ __launch_bounds__(256) void k_reduce_scan(
    u8* __restrict__ slab, float* __restrict__ rs_out, float* __restrict__ rs_in,
    int* __restrict__ partial, int* __restrict__ blocksum, u8* __restrict__ pad4,
    unsigned* __restrict__ csr_words, int ncw, int N)
{
    __shared__ int tmp[256];
    const int tid = threadIdx.x;
    const int i = blockIdx.x * 256 + tid;

    int run = 0;
    if (i < N) {
        const u8* s_src = slab + i;
        u8*       s_dst = slab + (size_t)HPS * NN + i;
        int so = 0;
#pragma unroll 8
        for (int p = 0; p < HPS; ++p) so += s_src[(size_t)p * NN];
#pragma unroll 8
        for (int p = 0; p < HPD; ++p) {
            const int c = s_dst[(size_t)p * NN];
            s_dst[(size_t)p * NN] = (u8)run;
            run += c;
        }
        rs_out[i] = rsqrtf(fmaxf((float)so, 1.0f));
        rs_in[i]  = rsqrtf(fmaxf((float)run, 1.0f));
    }
    const int pad = (run + 15) & ~15;            // pad degree to mult of 16
    if (i < N) pad4[i] = (u8)(pad >> 2);         // quarter length in entries
    tmp[tid] = pad; __syncthreads();
    for (int off = 1; off < 256; off <<= 1) {
        int t = (tid >= off) ? tmp[tid - off] : 0;
        __syncthreads(); tmp[tid] += t; __syncthreads();
    }
    if (i < N) partial[i] = tmp[tid];
    if (tid == 255) blocksum[blockIdx.x] = tmp[255];

    // dummy-init padded csr: every slot = node id NN (the zero row)
    for (int w = blockIdx.x * 256 + tid; w < ncw; w += gridDim.x * 256)
        csr_words[w] = 0xC350C350u;              // 0xC350 == 50000 == NN
}

// Fused scan2+scan3 -> seg[node] = (start, quarter_len_entries) uint2.
__global__ __launch_bounds__(256) void k_scan23(
    const int* __restrict__ partial, const int* __restrict__ blocksum,
    const u8* __restrict__ pad4, uint2* __restrict__ seg, int n, int nb)
{
    __shared__ int tmp[256];
    const int tid = threadIdx.x;
    int v = (tid < nb) ? blocksum[tid] : 0;
    tmp[tid] = v; __syncthreads();
    for (int off = 1; off < 256; off <<= 1) {
        int t = (tid >= off) ? tmp[tid - off] : 0;
        __syncthreads(); tmp[tid] += t; __syncthreads();
    }
    __syncthreads();
    const int i = blockIdx.x * 256 + tid;
    if (i < n) {
        const int base = (blockIdx.x > 0) ? tmp[blockIdx.x - 1] : 0;
        const int incl = partial[i] + base;
        const unsigned q = pad4[i];
        seg[i] = make_uint2((unsigned)(incl - (int)(q << 2)), q);
    }
}

// ---------- CSR fill: LDS cursors, u16 entries (zero global atomics) ----------
__global__ __launch_bounds__(256) void k_fill2(
    const int* __restrict__ src, const int* __restrict__ dst,
    const uint2* __restrict__ seg, const u8* __restrict__ slab,
    u16* __restrict__ csr, int E, int slice, int N)
{
    __shared__ int cur[FBIN];                    // 100KB
    const int bin = blockIdx.x / HPD;
    const int p   = blockIdx.x % HPD;
    const int lo  = bin * FBIN;

    const u8* part_off = slab + (size_t)(HPS + p) * NN;   // dst half, partition p
    for (int j = threadIdx.x; j < FBIN; j += 256) {
        const int node = lo + j;
        cur[j] = (int)seg[node].x + (int)part_off[node];
    }
    __syncthreads();

    const int beg = p * slice;
    const int fin = min(beg + slice, E);
    for (int i = beg + threadIdx.x * 4; i + 3 < fin; i += 1024) {
        const int4 d = *(const int4*)(dst + i);
        const int4 s = *(const int4*)(src + i);
        int u;
        u = d.x - lo; if ((unsigned)u < (unsigned)FBIN) csr[atomicAdd(&cur[u], 1)] = (u16)s.x;
        u = d.y - lo; if ((unsigned)u < (unsigned)FBIN) csr[atomicAdd(&cur[u], 1)] = (u16)s.y;
        u = d.z - lo; if ((unsigned)u < (unsigned)FBIN) csr[atomicAdd(&cur[u], 1)] = (u16)s.z;
        u = d.w - lo; if ((unsigned)u < (unsigned)FBIN) csr[atomicAdd(&cur[u], 1)] = (u16)s.w;
    }
    for (int i = beg + ((fin - beg) & ~3) + threadIdx.x; i < fin; i += 256) {
        int u = dst[i] - lo;
        if ((unsigned)u < (unsigned)FBIN) csr[atomicAdd(&cur[u], 1)] = (u16)src[i];
    }
}

// ---------------- MFMA GEMM A: t1b = bf16(rs_out .* (X @ W1)) ----------------
#define XS1 136    // padded bf16 row stride
__global__ __launch_bounds__(256) void k_gemm_mfma_A(
    const float* __restrict__ X, const float* __restrict__ W1,
    const float* __restrict__ rs, u16* __restrict__ Y,
    u16* __restrict__ t2b, u16* __restrict__ zb, int N)
{
    __shared__ u16 sXb[64 * XS1];     // X rows, bf16
    __shared__ u16 sWt[64 * XS1];     // W1^T: [n][k], bf16
    const int tid = threadIdx.x;
    const int m0 = blockIdx.x * 64;

    if (blockIdx.x == 0) {            // zero dummy rows (id NN)
        if (tid < 32)      ((unsigned*)(Y   + (size_t)NN * 64))[tid]      = 0;
        else if (tid < 48) ((unsigned*)(t2b + (size_t)NN * 32))[tid - 32] = 0;
        else if (tid < 64) ((unsigned*)(zb  + (size_t)NN * 32))[tid - 48] = 0;
    }

    for (int i = tid; i < 128 * 64; i += 256) {
        const int k = i >> 6, n = i & 63;
        sWt[n * XS1 + k] = (u16)f2bf(W1[i]);
    }
    for (int i = tid; i < 64 * 32; i += 256) {       // 64 rows x 32 float4-chunks
        const int r  = i >> 5;
        const int c4 = (i & 31) * 4;
        const int gr = m0 + r;
        float4 v = make_float4(0.f, 0.f, 0.f, 0.f);
        if (gr < N) v = *(const float4*)(X + (size_t)gr * 128 + c4);
        uint2 pk;
        pk.x = f2bf(v.x) | (f2bf(v.y) << 16);
        pk.y = f2bf(v.z) | (f2bf(v.w) << 16);
        *(uint2*)(sXb + r * XS1 + c4) = pk;
    }
    __syncthreads();

    const int wv   = tid >> 6;
    const int lane = tid & 63;
    const int l15  = lane & 15;
    const int quad = lane >> 4;

    f32x4 acc[4] = {};
    const u16* ax = sXb + (wv * 16 + l15) * XS1 + quad * 8;
    const u16* bx = sWt + l15 * XS1 + quad * 8;
#pragma unroll
    for (int ks = 0; ks < 4; ++ks) {
        const bf16x8 af = *(const bf16x8*)(ax + ks * 32);
#pragma unroll
        for (int nt = 0; nt < 4; ++nt) {
            const bf16x8 bf = *(const bf16x8*)(bx + nt * 16 * XS1 + ks * 32);
            acc[nt] = __builtin_amdgcn_mfma_f32_16x16x32_bf16(af, bf, acc[nt], 0, 0, 0);
        }
    }

    const int mrow = m0 + wv * 16 + quad * 4;
    float sc[4];
#pragma unroll
    for (int r = 0; r < 4; ++r) sc[r] = (mrow + r < N) ? rs[mrow + r] : 0.f;
#pragma unroll
    for (int r = 0; r < 4; ++r) {
        const int gr = mrow + r;
        if (gr < N) {
#pragma unroll
            for (int nt = 0; nt < 4; ++nt)
                Y[(size_t)gr * 64 + nt * 16 + l15] = (u16)f2bf(acc[nt][r] * sc[r]);
        }
    }
}

// accumulate one bf16x8 row chunk
#define ACC8(q) do { \
    a[0] += bflo((q).x); a[1] += bfhi((q).x); a[2] += bflo((q).y); a[3] += bfhi((q).y); \
    a[4] += bflo((q).z); a[5] += bfhi((q).z); a[6] += bflo((q).w); a[7] += bfhi((q).w); } while (0)

// gather 4 padded edges: 1 uint2 index load + 4 row loads
#define GATHER4(SRCB, RW) do { \
    const uint2 w = *(const uint2*)(csr + j); \
    const int s0 = w.x & 0xFFFF, s1 = w.x >> 16; \
    const int s2 = w.y & 0xFFFF, s3 = w.y >> 16; \
    const uint4 q0 = *(const uint4*)(SRCB + (size_t)s0 * RW + c8); \
    const uint4 q1 = *(const uint4*)(SRCB + (size_t)s1 * RW + c8); \
    const uint4 q2 = *(const uint4*)(SRCB + (size_t)s2 * RW + c8); \
    const uint4 q3 = *(const uint4*)(SRCB + (size_t)s3 * RW + c8); \
    ACC8(q0); ACC8(q1); ACC8(q2); ACC8(q3); } while (0)

// ---------------- fused B: gather(t1b,64) + relu + @W2 -> t2b ----------------
// 32 nodes/block: 4 gather batches (8 nodes x 32 lanes), then 256-thread GEMM.
__global__ __launch_bounds__(256) void k_gather_gemm_B(
    const uint2* __restrict__ seg, const u16* __restrict__ csr,
    const u16* __restrict__ t1b, const float* __restrict__ rs_in,
    const float* __restrict__ rs_out, const float* __restrict__ b1,
    const float* __restrict__ W2, u16* __restrict__ t2b, int N)
{
    __shared__ float sh[32][72];
    __shared__ float sW[64 * 32];
    const int tid = threadIdx.x;

    for (int i = tid; i < 64 * 32 / 4; i += 256)
        ((float4*)sW)[i] = ((const float4*)W2)[i];

    const int nb   = tid >> 5;           // 8 node-groups in flight
    const int sub  = tid & 31;
    const int qtr  = sub >> 3;
    const int c8   = (sub & 7) * 8;

    uint2 sgs[4];                        // preload all batches' segments
#pragma unroll
    for (int b = 0; b < 4; ++b) {
        const int node = blockIdx.x * 32 + b * 8 + nb;
        sgs[b] = (node < N) ? seg[node] : make_uint2(0u, 0u);
    }

#pragma unroll
    for (int b = 0; b < 4; ++b) {
        const int nloc = b * 8 + nb;
        const int node = blockIdx.x * 32 + nloc;
        float a[8];
#pragma unroll
        for (int t = 0; t < 8; ++t) a[t] = 0.f;
        const int j0 = (int)sgs[b].x + qtr * (int)sgs[b].y;
        const int j1 = j0 + (int)sgs[b].y;
        for (int j = j0; j < j1; j += 4) GATHER4(t1b, 64);
#pragma unroll
        for (int t = 0; t < 8; ++t) {
            a[t] += __shfl_xor(a[t], 8);
            a[t] += __shfl_xor(a[t], 16);
        }
        if (node < N && qtr == 0) {
            const float rs = rs_in[node];
#pragma unroll
            for (int t = 0; t < 8; ++t)
                sh[nloc][c8 + t] = fmaxf(a[t] * rs + b1[c8 + t], 0.f);
        }
    }
    __syncthreads();

    // GEMM: 32 nodes x 32 cols; all 256 threads (node=tid/8, 4 cols each)
    const int n2 = tid >> 3;
    const int c4 = (tid & 7) * 4;
    float4 acc = make_float4(0.f, 0.f, 0.f, 0.f);
#pragma unroll 8
    for (int k = 0; k < 64; ++k) {
        const float xv = sh[n2][k];
        const float4 w = *(const float4*)(sW + k * 32 + c4);
        acc.x += xv * w.x; acc.y += xv * w.y; acc.z += xv * w.z; acc.w += xv * w.w;
    }
    const int gn = blockIdx.x * 32 + n2;
    if (gn < N) {
        const float s = rs_out[gn];
        uint2 pk;
        pk.x = f2bf(acc.x * s) | (f2bf(acc.y * s) << 16);
        pk.y = f2bf(acc.z * s) | (f2bf(acc.w * s) << 16);
        *(uint2*)(t2b + (size_t)gn * 32 + c4) = pk;
    }
}

// ---------------- C: gather(t2b,32) -> z (f32, d_out) + zb shadow ----------------
// 16 lanes/node = 4 col-lanes x 4 edge-quarters; combine via shfl_xor 4,8.
__global__ __launch_bounds__(256) void k_gather_C(
    const uint2* __restrict__ seg, const u16* __restrict__ csr,
    const u16* __restrict__ t2b, const float* __restrict__ rs_in,
    const float* __restrict__ rs_out, const float* __restrict__ b2,
    float* __restrict__ z, u16* __restrict__ zb, int N)
{
    const int node = blockIdx.x * 16 + (threadIdx.x >> 4);
    const int sub  = threadIdx.x & 15;
    const int qtr  = sub >> 2;
    const int c8   = (sub & 3) * 8;
    if (node >= N) return;               // 16-lane group exits together

    const uint2 sg = seg[node];
    const int j0 = (int)sg.x + qtr * (int)sg.y;
    const int j1 = j0 + (int)sg.y;

    float a[8];
#pragma unroll
    for (int t = 0; t < 8; ++t) a[t] = 0.f;
    for (int j = j0; j < j1; j += 4) GATHER4(t2b, 32);

#pragma unroll
    for (int t = 0; t < 8; ++t) {
        a[t] += __shfl_xor(a[t], 4);
        a[t] += __shfl_xor(a[t], 8);
    }
    if (qtr) return;

    const float rs = rs_in[node];
    float v[8];
#pragma unroll
    for (int t = 0; t < 8; ++t) v[t] = a[t] * rs + b2[c8 + t];

    float* o = z + (size_t)node * 32 + c8;
    *(float4*)(o)     = make_float4(v[0], v[1], v[2], v[3]);
    *(float4*)(o + 4) = make_float4(v[4], v[5], v[6], v[7]);

    const float ss = rs_out[node];
    uint4 pk;
    pk.x = f2bf(v[0] * ss) | (f2bf(v[1] * ss) << 16);
    pk.y = f2bf(v[2] * ss) | (f2bf(v[3] * ss) << 16);
    pk.z = f2bf(v[4] * ss) | (f2bf(v[5] * ss) << 16);
    pk.w = f2bf(v[6] * ss) | (f2bf(v[7] * ss) << 16);
    *(uint4*)(zb + (size_t)node * 32 + c8) = pk;
}

// ---------------- fused D: gather(zb,32) + @W3 + b3 -> recon ----------------
// 32 nodes/block: 2 gather batches (16 nodes x 16 lanes), then 256-thread GEMM.
__global__ __launch_bounds__(256) void k_gather_gemm_D(
    const uint2* __restrict__ seg, const u16* __restrict__ csr,
    const u16* __restrict__ zb, const float* __restrict__ rs_in,
    const float* __restrict__ W3, const float* __restrict__ b3,
    float* __restrict__ recon, int N)
{
    __shared__ float sa[32][36];
    __shared__ float sW[32 * 128];
    const int tid = threadIdx.x;

    for (int i = tid; i < 32 * 128 / 4; i += 256)
        ((float4*)sW)[i] = ((const float4*)W3)[i];

    const int nb   = tid >> 4;           // 16 node-groups in flight
    const int sub  = tid & 15;
    const int qtr  = sub >> 2;
    const int c8   = (sub & 3) * 8;

    uint2 sgs[2];                        // preload both batches' segments
#pragma unroll
    for (int b = 0; b < 2; ++b) {
        const int node = blockIdx.x * 32 + b * 16 + nb;
        sgs[b] = (node < N) ? seg[node] : make_uint2(0u, 0u);
    }

#pragma unroll
    for (int b = 0; b < 2; ++b) {
        const int nloc = b * 16 + nb;
        const int node = blockIdx.x * 32 + nloc;
        float a[8];
#pragma unroll
        for (int t = 0; t < 8; ++t) a[t] = 0.f;
        const int j0 = (int)sgs[b].x + qtr * (int)sgs[b].y;
        const int j1 = j0 + (int)sgs[b].y;
        for (int j = j0; j < j1; j += 4) GATHER4(zb, 32);
#pragma unroll
        for (int t = 0; t < 8; ++t) {
            a[t] += __shfl_xor(a[t], 4);
            a[t] += __shfl_xor(a[t], 8);
        }
        if (node < N && qtr == 0) {
            const float rs = rs_in[node];
#pragma unroll
            for (int t = 0; t < 8; ++t) sa[nloc][c8 + t] = a[t] * rs;
        }
    }
    __syncthreads();

    // GEMM: 32 nodes x 128 cols; thread -> 4 nodes x 4 cols
    const int ng = (tid >> 5) * 4;
    const int c4 = (tid & 31) * 4;
    const float4 bb = *(const float4*)(b3 + c4);
    float4 acc[4];
#pragma unroll
    for (int i = 0; i < 4; ++i) acc[i] = bb;
#pragma unroll 4
    for (int k = 0; k < 32; ++k) {
        const float4 w = *(const float4*)(sW + k * 128 + c4);
#pragma unroll
        for (int i = 0; i < 4; ++i) {
            const float xv = sa[ng + i][k];
            acc[i].x += xv * w.x; acc[i].y += xv * w.y;
            acc[i].z += xv * w.z; acc[i].w += xv * w.w;
        }
    }
#pragma unroll
    for (int i = 0; i < 4; ++i) {
        const int gn = blockIdx.x * 32 + ng + i;
        if (gn < N) *(float4*)(recon + (size_t)gn * 128 + c4) = acc[i];
    }
}

extern "C" void kernel_launch(void* const* d_in, const int* in_sizes, int n_in,
                              void* d_out, int out_size, void* d_ws, size_t ws_size,
                              hipStream_t stream) {
    const float* feat = (const float*)d_in[0];   // [N,128]
    const int*   src  = (const int*)d_in[1];     // [E]
    const int*   dst  = (const int*)d_in[2];     // [E]
    const float* W1   = (const float*)d_in[3];   // [128,64]
    const float* b1   = (const float*)d_in[4];   // [64]
    const float* W2   = (const float*)d_in[5];   // [64,32]
    const float* b2   = (const float*)d_in[6];   // [32]
    const float* W3   = (const float*)d_in[7];   // [32,128]
    const float* b3   = (const float*)d_in[8];   // [128]

    const int E = in_sizes[1];
    const int N = in_sizes[0] / 128;             // 50000 == NN
    const int slice_s = (((E + HPS - 1) / HPS) + 3) & ~3;
    const int slice_d = (((E + HPD - 1) / HPD) + 3) & ~3;
    const int CSRMAX = E + 15 * N;               // padded-csr upper bound (entries)
    const int ncw = CSRMAX / 2;                  // u32 words

    // ---- workspace layout (16B alignment at every boundary) ----
    const size_t SLABB = (size_t)(HPS + HPD) * NN;  // u8 slab = 8MB
    u8*  slab     = (u8*)d_ws;                    // dead after k_fill2
    uint2* seg    = (uint2*)(slab + SLABB);       // [N+16] (start, qlen)
    int* scan_p   = (int*)(seg + N + 16);         // [N]
    int* blocksum = scan_p + N;                   // [256]
    u16* csr      = (u16*)(blocksum + 256);       // [CSRMAX] u16 node ids
    float* rs_out = (float*)(csr + CSRMAX);       // [N]
    float* rs_in  = rs_out + N;                   // [N]
    u16* t2b      = (u16*)(rs_in + N);            // [(N+8),32] bf16 (+dummy row N)
    u16* zb       = t2b + (size_t)(N + 8) * 32;   // [(N+8),32] bf16 (z * rs_out)
    u8*  pad4     = (u8*)(zb + (size_t)(N + 8) * 32);  // [N] quarter lengths
    u16* t1b      = (u16*)slab;                   // [(N+1),64] bf16 = 6.4MB <= slab

    float* z_out  = (float*)d_out;                // [N,32]
    float* recon  = z_out + (size_t)N * 32;       // [N,128]

    const int B = 256;
    const int nb_scan = (N + 255) / 256;          // 196

    // ---- atomic-free graph preprocessing (padded CSR, u8 counts, u16 ids) ----
    k_hist1<<<HPS + HPD, B, 0, stream>>>(src, dst, slab, E, slice_s, slice_d);
    k_reduce_scan<<<nb_scan, B, 0, stream>>>(slab, rs_out, rs_in, scan_p, blocksum,
                                             pad4, (unsigned*)csr, ncw, N);
    k_scan23<<<nb_scan, B, 0, stream>>>(scan_p, blocksum, pad4, seg, N, nb_scan);
    k_fill2<<<FNB * HPD, B, 0, stream>>>(src, dst, seg, slab, csr, E, slice_d, N);

    // ---- A: t1b = bf16(rs_out .* (X @ W1)) via MFMA; zero dummy rows ----
    k_gemm_mfma_A<<<(N + 63) / 64, B, 0, stream>>>(
        feat, W1, rs_out, t1b, t2b, zb, N);

    // ---- B: gather(t1b) + relu + @W2 -> t2b ----
    k_gather_gemm_B<<<(N + 31) / 32, B, 0, stream>>>(
        seg, csr, t1b, rs_in, rs_out, b1, W2, t2b, N);

    // ---- C: gather(t2b) -> z (d_out) + zb shadow ----
    k_gather_C<<<(N + 15) / 16, B, 0, stream>>>(
        seg, csr, t2b, rs_in, rs_out, b2, z_out, zb, N);

    // ---- D: gather(zb) + @W3 + b3 -> recon ----
    k_gather_gemm_D<<<(N + 31) / 32, B, 0, stream>>>(
        seg, csr, zb, rs_in, W3, b3, recon, N);
}